// Round 8
// baseline (237.779 us; speedup 1.0000x reference)
//
#include <hip/hip_runtime.h>
#include <hip/hip_bf16.h>

#define NCH 256      // C
#define NHD 8        // heads
#define HD 32        // head dim
#define NPIX 2304    // 48*48
#define H1DIM 512

typedef __attribute__((ext_vector_type(8))) __bf16 bf16x8;
typedef __attribute__((ext_vector_type(4))) float f32x4;

// ---------------- prep: x NCHW f32 -> NHWC bf16  +  weight cast --------------
// blocks [0,288): transpose;  blocks [288,800): weight cast (5 matrices)
__global__ __launch_bounds__(256) void prep_k(
    const float* __restrict__ x,
    const float* __restrict__ w0, const float* __restrict__ w1,
    const float* __restrict__ w2, const float* __restrict__ w3,
    const float* __restrict__ w4,
    __bf16* __restrict__ Xb, __bf16* __restrict__ Wall) {
    const int tid = threadIdx.x;
    if (blockIdx.x < 288) {
        const int t = blockIdx.x;
        const int b = t / 144, r0 = t % 144;
        const int c0 = (r0 / 36) * 64, n0 = (r0 % 36) * 64;
        __shared__ float tile[64][65];
        const size_t sb = ((size_t)b * NCH + c0) * NPIX + n0;
#pragma unroll
        for (int i = 0; i < 16; ++i) {
            int idx = tid + i * 256;
            int rr = idx >> 6, cc = idx & 63;
            tile[rr][cc] = x[sb + (size_t)rr * NPIX + cc];
        }
        __syncthreads();
#pragma unroll
        for (int i = 0; i < 8; ++i) {
            int idx = tid + i * 256;
            int nn = idx >> 5, cp = (idx & 31) * 2;
            union { __bf16 h[2]; unsigned u; } pk;
            pk.h[0] = (__bf16)tile[cp][nn];
            pk.h[1] = (__bf16)tile[cp + 1][nn];
            *(unsigned*)&Xb[((size_t)b * NPIX + n0 + nn) * NCH + c0 + cp] = pk.u;
        }
    } else {
        int i = (blockIdx.x - 288) * 256 + tid;   // quad index over 131072
        const float* src; int off;
        if (i < 32768)      { src = w0; off = i; }
        else if (i < 49152) { src = w1; off = i - 32768; }
        else if (i < 65536) { src = w2; off = i - 49152; }
        else if (i < 98304) { src = w3; off = i - 65536; }
        else                { src = w4; off = i - 98304; }
        float4 v = ((const float4*)src)[off];
        union { __bf16 h[4]; uint2 u; } pk;
        pk.h[0] = (__bf16)v.x; pk.h[1] = (__bf16)v.y;
        pk.h[2] = (__bf16)v.z; pk.h[3] = (__bf16)v.w;
        ((uint2*)Wall)[i] = pk.u;
    }
}

// ---------------- fused qk+v conv ----------------
// grid (36, 48, B), block 256 = 4 waves; wave: 16 px x 16 oc, IC=256.
// y<32: qk (oc=y*16 of 512) -> Qb (scaled bf16) + Kf frag tiles
// y>=32: v (oc=(y-32)*16 of 256) -> v_bu NCHW f32 + Vf frag tiles
__global__ __launch_bounds__(256) void qkv_k(
    const __bf16* __restrict__ A, const __bf16* __restrict__ Wq,
    const __bf16* __restrict__ Wv, const float* __restrict__ qk_b,
    const float* __restrict__ v_b, __bf16* __restrict__ Qb,
    __bf16* __restrict__ Kf, float* __restrict__ v_bu,
    __bf16* __restrict__ Vf) {
    const int tid = threadIdx.x;
    const int wave = tid >> 6, lane = tid & 63;
    const int l16 = lane & 15, quad = lane >> 4;
    const int m0 = blockIdx.x * 64 + wave * 16;
    const int b = blockIdx.z;
    const bool isv = blockIdx.y >= 32;
    const int oc0 = (isv ? (blockIdx.y - 32) : blockIdx.y) * 16;
    const __bf16* W = isv ? Wv : Wq;

    const __bf16* aptr = A + ((size_t)b * NPIX + m0 + l16) * NCH + quad * 8;
    const __bf16* bptr = W + (size_t)(oc0 + l16) * NCH + quad * 8;

    f32x4 acc = {0.f, 0.f, 0.f, 0.f};
#pragma unroll 8
    for (int k = 0; k < NCH; k += 32) {
        bf16x8 af = *(const bf16x8*)(aptr + k);
        bf16x8 bf = *(const bf16x8*)(bptr + k);
        acc = __builtin_amdgcn_mfma_f32_16x16x32_bf16(af, bf, acc, 0, 0, 0);
    }

    const int oc = oc0 + l16;
    const int mb = m0 + quad * 4;

    if (!isv) {
        const float bb = qk_b[oc];
        const int h = oc0 >> 6;
        const int bh = b * NHD + h;
        const int dd = (oc0 & 16) + l16;
        if ((oc0 & 32) == 0) {
            const float qs = 0.17677669529663689f * 1.4426950408889634f;  // hd^-0.5 * log2e
#pragma unroll
            for (int r = 0; r < 4; ++r)
                Qb[((size_t)bh * NPIX + mb + r) * 32 + dd] = (__bf16)((acc[r] + bb) * qs);
        } else {
            __bf16* kp = Kf + ((size_t)(bh * 144 + (m0 >> 4)) * 64 + (dd >> 3) * 16 + quad * 4) * 8 + (dd & 7);
#pragma unroll
            for (int r = 0; r < 4; ++r) kp[r * 8] = (__bf16)(acc[r] + bb);
        }
    } else {
        const float bb = v_b[oc];
        const int h = oc0 >> 5;
        const int bh = b * NHD + h;
        const int half = (oc0 >> 4) & 1;
        const size_t fb = ((size_t)b * NCH + oc) * NPIX + mb;
        float4 vf_; float* vp = &vf_.x;
        union { __bf16 hh[4]; uint2 u; } pk;
#pragma unroll
        for (int r = 0; r < 4; ++r) {
            float v = acc[r] + bb;
            vp[r] = v; pk.hh[r] = (__bf16)v;
        }
        *(float4*)&v_bu[fb] = vf_;
        *(uint2*)&Vf[((size_t)(bh * 144 + (m0 >> 4)) * 64 + lane) * 8 + half * 4] = pk.u;
    }
}

// ---------------- MFMA 1x1 conv (proj/fc1/fc2), 4-wave blocks ----------------
// MODE 2: proj -> +resid(NCHW f32); out_f NCHW f32 (x1) + out_b NHWC bf16 (x1)
// MODE 3: fc1  -> silu; out_b NHWC bf16
// MODE 4: fc2  -> +resid(NCHW f32); out_f NCHW f32 (final)
template <int IC, int OC, int MODE>
__global__ __launch_bounds__(256) void convmm_k(
    const __bf16* __restrict__ A, const __bf16* __restrict__ W,
    const float* __restrict__ bias, const float* __restrict__ resid,
    float* __restrict__ out_f, __bf16* __restrict__ out_b) {
    const int tid = threadIdx.x;
    const int wave = tid >> 6, lane = tid & 63;
    const int l16 = lane & 15, quad = lane >> 4;
    const int m0 = blockIdx.x * 64 + wave * 16;
    const int oc0 = blockIdx.y * 16;
    const int b = blockIdx.z;

    const __bf16* aptr = A + ((size_t)b * NPIX + m0 + l16) * IC + quad * 8;
    const __bf16* bptr = W + (size_t)(oc0 + l16) * IC + quad * 8;

    f32x4 acc = {0.f, 0.f, 0.f, 0.f};
#pragma unroll 8
    for (int k = 0; k < IC; k += 32) {
        bf16x8 af = *(const bf16x8*)(aptr + k);
        bf16x8 bf = *(const bf16x8*)(bptr + k);
        acc = __builtin_amdgcn_mfma_f32_16x16x32_bf16(af, bf, acc, 0, 0, 0);
    }

    const int oc = oc0 + l16;
    const int mb = m0 + quad * 4;
    const float bb = bias[oc];

    if constexpr (MODE == 2) {
        const size_t fb = ((size_t)b * OC + oc) * NPIX + mb;
        float4 xr = *(const float4*)&resid[fb];
        const float* xp = &xr.x;
        float4 vf_; float* vp = &vf_.x;
#pragma unroll
        for (int r = 0; r < 4; ++r) {
            float v = acc[r] + bb + xp[r];
            vp[r] = v;
            out_b[((size_t)b * NPIX + mb + r) * OC + oc] = (__bf16)v;
        }
        *(float4*)&out_f[fb] = vf_;
    } else if constexpr (MODE == 3) {
#pragma unroll
        for (int r = 0; r < 4; ++r) {
            float v = acc[r] + bb;
            v = v / (1.f + __expf(-v));
            out_b[((size_t)b * NPIX + mb + r) * OC + oc] = (__bf16)v;
        }
    } else {  // MODE 4
        const size_t fb = ((size_t)b * OC + oc) * NPIX + mb;
        float4 xr = *(const float4*)&resid[fb];
        const float* xp = &xr.x;
        float4 vf_; float* vp = &vf_.x;
#pragma unroll
        for (int r = 0; r < 4; ++r) vp[r] = acc[r] + bb + xp[r];
        *(float4*)&out_f[fb] = vf_;
    }
}

// ---------------- depthwise 7x7, SAME, per (b,c) plane ----------------
__global__ __launch_bounds__(256) void dwconv_k(const float* __restrict__ vb,
                                                const float* __restrict__ pw,
                                                const float* __restrict__ pb,
                                                float* __restrict__ pe) {
    const int c = blockIdx.x, b = blockIdx.y, tid = threadIdx.x;
    __shared__ float plane[NPIX];
    __shared__ float wk[49];
    const size_t base = ((size_t)b * NCH + c) * NPIX;
    for (int i = tid; i < NPIX; i += 256) plane[i] = vb[base + i];
    if (tid < 49) wk[tid] = pw[c * 49 + tid];
    float bb = pb[c];
    __syncthreads();
    for (int p = tid; p < NPIX; p += 256) {
        int y = p / 48, x = p - y * 48;
        float s = bb;
#pragma unroll
        for (int ky = 0; ky < 7; ++ky) {
            int yy = y + ky - 3;
            if ((unsigned)yy < 48u) {
#pragma unroll
                for (int kx = 0; kx < 7; ++kx) {
                    int xx = x + kx - 3;
                    if ((unsigned)xx < 48u) s += wk[ky * 7 + kx] * plane[yy * 48 + xx];
                }
            }
        }
        pe[base + p] = s;
    }
}

// ---------------- MFMA flash attention v5: single pass, fused epilogue -------
// 1-wave WGs (64 thr), 32 queries/wave, full 2304 keys (144 tiles).
// Normalizes in-kernel, adds pe, writes NHWC bf16 opb directly. No splits,
// no merge, no LDS, no barriers, no running max (|s| small by construction).
// grid (NPIX/32, NH, B)
__global__ __launch_bounds__(64) void attn5_k(const __bf16* __restrict__ Qb,
                                              const __bf16* __restrict__ Kf,
                                              const __bf16* __restrict__ Vf,
                                              const float* __restrict__ pe,
                                              __bf16* __restrict__ opb) {
    const int lane = threadIdx.x;
    const int l16 = lane & 15, quad = lane >> 4;
    const int qb = blockIdx.x * 32;
    const int h = blockIdx.y, b = blockIdx.z;
    const int bh = b * NHD + h;

    bf16x8 b_q0 = *(const bf16x8*)(Qb + ((size_t)bh * NPIX + qb + l16) * 32 + quad * 8);
    bf16x8 b_q1 = *(const bf16x8*)(Qb + ((size_t)bh * NPIX + qb + 16 + l16) * 32 + quad * 8);

    const __bf16* kf = Kf + ((size_t)(bh * 144) * 64 + lane) * 8;
    const __bf16* vf = Vf + ((size_t)(bh * 144) * 64 + lane) * 8;

    f32x4 o00 = {0.f,0.f,0.f,0.f}, o01 = {0.f,0.f,0.f,0.f};
    f32x4 o10 = {0.f,0.f,0.f,0.f}, o11 = {0.f,0.f,0.f,0.f};
    f32x4 l0 = {0.f,0.f,0.f,0.f}, l1 = {0.f,0.f,0.f,0.f};

#pragma unroll 4
    for (int t = 0; t < 144; ++t) {
        bf16x8 a_k = *(const bf16x8*)(kf + (size_t)t * 512);
        bf16x8 va  = *(const bf16x8*)(vf + (size_t)t * 512);
        f32x4 z = {0.f, 0.f, 0.f, 0.f};
        f32x4 s0 = __builtin_amdgcn_mfma_f32_16x16x32_bf16(a_k, b_q0, z, 0, 0, 0);
        f32x4 s1 = __builtin_amdgcn_mfma_f32_16x16x32_bf16(a_k, b_q1, z, 0, 0, 0);
        f32x4 p0, p1;
#pragma unroll
        for (int r = 0; r < 4; ++r) {
            p0[r] = __builtin_amdgcn_exp2f(s0[r]);
            p1[r] = __builtin_amdgcn_exp2f(s1[r]);
        }
        l0 += p0; l1 += p1;
        bf16x8 b0lo = {}, b0hi = {}, b1lo = {}, b1hi = {};
#pragma unroll
        for (int r = 0; r < 4; ++r) {
            __bf16 c0 = (__bf16)p0[r], c1 = (__bf16)p1[r];
            b0lo[r] = c0; b0hi[4 + r] = c0;
            b1lo[r] = c1; b1hi[4 + r] = c1;
        }
        o00 = __builtin_amdgcn_mfma_f32_16x16x32_bf16(va, b0lo, o00, 0, 0, 0);
        o01 = __builtin_amdgcn_mfma_f32_16x16x32_bf16(va, b0hi, o01, 0, 0, 0);
        o10 = __builtin_amdgcn_mfma_f32_16x16x32_bf16(va, b1lo, o10, 0, 0, 0);
        o11 = __builtin_amdgcn_mfma_f32_16x16x32_bf16(va, b1hi, o11, 0, 0, 0);
    }

    float ls0 = l0[0] + l0[1] + l0[2] + l0[3];
    ls0 += __shfl_xor(ls0, 16); ls0 += __shfl_xor(ls0, 32);
    float ls1 = l1[0] + l1[1] + l1[2] + l1[3];
    ls1 += __shfl_xor(ls1, 16); ls1 += __shfl_xor(ls1, 32);
    const float inv0 = 1.f / ls0, inv1 = 1.f / ls1;

    const int n0 = qb + l16, n1 = qb + 16 + l16;
    const int ch0 = h * HD + quad * 4;
#pragma unroll
    for (int r = 0; r < 4; ++r) {
        const int ca = ch0 + r, cb = ch0 + 16 + r;
        float pa0 = pe[((size_t)b * NCH + ca) * NPIX + n0];
        float pb0 = pe[((size_t)b * NCH + cb) * NPIX + n0];
        float pa1 = pe[((size_t)b * NCH + ca) * NPIX + n1];
        float pb1 = pe[((size_t)b * NCH + cb) * NPIX + n1];
        opb[((size_t)b * NPIX + n0) * NCH + ca] = (__bf16)(o00[r] * inv0 + pa0);
        opb[((size_t)b * NPIX + n0) * NCH + cb] = (__bf16)(o01[r] * inv0 + pb0);
        opb[((size_t)b * NPIX + n1) * NCH + ca] = (__bf16)(o10[r] * inv1 + pa1);
        opb[((size_t)b * NPIX + n1) * NCH + cb] = (__bf16)(o11[r] * inv1 + pb1);
    }
}

extern "C" void kernel_launch(void* const* d_in, const int* in_sizes, int n_in,
                              void* d_out, int out_size, void* d_ws, size_t ws_size,
                              hipStream_t stream) {
    const float* x    = (const float*)d_in[0];
    const float* qk_w = (const float*)d_in[1];
    const float* qk_b = (const float*)d_in[2];
    const float* v_w  = (const float*)d_in[3];
    const float* v_b  = (const float*)d_in[4];
    const float* pe_w = (const float*)d_in[5];
    const float* pe_b = (const float*)d_in[6];
    const float* pj_w = (const float*)d_in[7];
    const float* pj_b = (const float*)d_in[8];
    const float* f1_w = (const float*)d_in[9];
    const float* f1_b = (const float*)d_in[10];
    const float* f2_w = (const float*)d_in[11];
    const float* f2_b = (const float*)d_in[12];
    float* out = (float*)d_out;

    const int B = 2;
    const size_t plane = (size_t)NCH * NPIX;       // 589824
    const size_t bp = (size_t)B * plane;           // 1179648

    float* v_bu  = (float*)d_ws;                   // NCHW f32
    float* pe_bu = v_bu + bp;
    float* x1_f  = pe_bu + bp;
    __bf16* Xb   = (__bf16*)(x1_f + bp);           // NHWC bf16 [b][n][256]
    __bf16* opb  = Xb + bp;                        // NHWC bf16 (o/l + pe)
    __bf16* x1b  = opb + bp;                       // NHWC bf16
    __bf16* hb   = x1b + bp;                       // NHWC bf16 [b][n][512]
    __bf16* Qb   = hb + 2 * bp;                    // [bh][n][32] (pre-scaled)
    __bf16* Kf   = Qb + bp;                        // QK A-frag tiles
    __bf16* Vf   = Kf + bp;                        // PV A-frag tiles
    __bf16* Wall = Vf + bp;                        // 524288 bf16
    __bf16* Wq = Wall;
    __bf16* Wv = Wall + 131072;
    __bf16* Wp = Wall + 196608;
    __bf16* W1 = Wall + 262144;
    __bf16* W2 = Wall + 393216;

    // 1) x transpose + all weight casts
    prep_k<<<800, 256, 0, stream>>>(x, qk_w, v_w, pj_w, f1_w, f2_w, Xb, Wall);
    // 2) qk conv (-> Qb, Kf) + v conv (-> v_bu f32, Vf) fused
    qkv_k<<<dim3(36, 48, B), 256, 0, stream>>>(Xb, Wq, Wv, qk_b, v_b, Qb, Kf, v_bu, Vf);
    // 3) pe = dwconv7x7(v_full) + pe_b
    dwconv_k<<<dim3(NCH, B), 256, 0, stream>>>(v_bu, pe_w, pe_b, pe_bu);
    // 4) attention: single pass, normalize + pe add -> opb NHWC bf16
    attn5_k<<<dim3(NPIX / 32, NHD, B), 64, 0, stream>>>(Qb, Kf, Vf, pe_bu, opb);
    // 5) x1 = x + proj(o+pe): NCHW f32 + NHWC bf16
    convmm_k<256, 256, 2><<<dim3(36, 16, B), 256, 0, stream>>>(
        opb, Wp, pj_b, x, x1_f, x1b);
    // 6) h = silu(fc1(x1)) -> NHWC bf16
    convmm_k<256, 512, 3><<<dim3(36, 32, B), 256, 0, stream>>>(
        x1b, W1, f1_b, nullptr, nullptr, hb);
    // 7) out = x1 + fc2(h) -> NCHW f32
    convmm_k<512, 256, 4><<<dim3(36, 16, B), 256, 0, stream>>>(
        hb, W2, f2_b, x1_f, out, nullptr);
}

// Round 9
// 210.665 us; speedup vs baseline: 1.1287x; 1.1287x over previous
//
#include <hip/hip_runtime.h>
#include <hip/hip_bf16.h>

#define NCH 256      // C
#define NHD 8        // heads
#define HD 32        // head dim
#define NPIX 2304    // 48*48
#define H1DIM 512

typedef __attribute__((ext_vector_type(8))) __bf16 bf16x8;
typedef __attribute__((ext_vector_type(4))) float f32x4;

// ---------------- prep: x NCHW f32 -> NHWC bf16  +  weight cast --------------
// blocks [0,288): transpose;  blocks [288,800): weight cast (5 matrices)
__global__ __launch_bounds__(256) void prep_k(
    const float* __restrict__ x,
    const float* __restrict__ w0, const float* __restrict__ w1,
    const float* __restrict__ w2, const float* __restrict__ w3,
    const float* __restrict__ w4,
    __bf16* __restrict__ Xb, __bf16* __restrict__ Wall) {
    const int tid = threadIdx.x;
    if (blockIdx.x < 288) {
        const int t = blockIdx.x;
        const int b = t / 144, r0 = t % 144;
        const int c0 = (r0 / 36) * 64, n0 = (r0 % 36) * 64;
        __shared__ float tile[64][65];
        const size_t sb = ((size_t)b * NCH + c0) * NPIX + n0;
#pragma unroll
        for (int i = 0; i < 16; ++i) {
            int idx = tid + i * 256;
            int rr = idx >> 6, cc = idx & 63;
            tile[rr][cc] = x[sb + (size_t)rr * NPIX + cc];
        }
        __syncthreads();
#pragma unroll
        for (int i = 0; i < 8; ++i) {
            int idx = tid + i * 256;
            int nn = idx >> 5, cp = (idx & 31) * 2;
            union { __bf16 h[2]; unsigned u; } pk;
            pk.h[0] = (__bf16)tile[cp][nn];
            pk.h[1] = (__bf16)tile[cp + 1][nn];
            *(unsigned*)&Xb[((size_t)b * NPIX + n0 + nn) * NCH + c0 + cp] = pk.u;
        }
    } else {
        int i = (blockIdx.x - 288) * 256 + tid;   // quad index over 131072
        const float* src; int off;
        if (i < 32768)      { src = w0; off = i; }
        else if (i < 49152) { src = w1; off = i - 32768; }
        else if (i < 65536) { src = w2; off = i - 49152; }
        else if (i < 98304) { src = w3; off = i - 65536; }
        else                { src = w4; off = i - 98304; }
        float4 v = ((const float4*)src)[off];
        union { __bf16 h[4]; uint2 u; } pk;
        pk.h[0] = (__bf16)v.x; pk.h[1] = (__bf16)v.y;
        pk.h[2] = (__bf16)v.z; pk.h[3] = (__bf16)v.w;
        ((uint2*)Wall)[i] = pk.u;
    }
}

// ---------------- fused qk+v conv ----------------
// grid (36, 48, B), block 256 = 4 waves; wave: 16 px x 16 oc, IC=256.
// y<32: qk (oc=y*16 of 512) -> Qb (scaled bf16) + Kf frag tiles
// y>=32: v (oc=(y-32)*16 of 256) -> v_bu NCHW f32 + Vf frag tiles
__global__ __launch_bounds__(256) void qkv_k(
    const __bf16* __restrict__ A, const __bf16* __restrict__ Wq,
    const __bf16* __restrict__ Wv, const float* __restrict__ qk_b,
    const float* __restrict__ v_b, __bf16* __restrict__ Qb,
    __bf16* __restrict__ Kf, float* __restrict__ v_bu,
    __bf16* __restrict__ Vf) {
    const int tid = threadIdx.x;
    const int wave = tid >> 6, lane = tid & 63;
    const int l16 = lane & 15, quad = lane >> 4;
    const int m0 = blockIdx.x * 64 + wave * 16;
    const int b = blockIdx.z;
    const bool isv = blockIdx.y >= 32;
    const int oc0 = (isv ? (blockIdx.y - 32) : blockIdx.y) * 16;
    const __bf16* W = isv ? Wv : Wq;

    const __bf16* aptr = A + ((size_t)b * NPIX + m0 + l16) * NCH + quad * 8;
    const __bf16* bptr = W + (size_t)(oc0 + l16) * NCH + quad * 8;

    f32x4 acc = {0.f, 0.f, 0.f, 0.f};
#pragma unroll 8
    for (int k = 0; k < NCH; k += 32) {
        bf16x8 af = *(const bf16x8*)(aptr + k);
        bf16x8 bf = *(const bf16x8*)(bptr + k);
        acc = __builtin_amdgcn_mfma_f32_16x16x32_bf16(af, bf, acc, 0, 0, 0);
    }

    const int oc = oc0 + l16;
    const int mb = m0 + quad * 4;

    if (!isv) {
        const float bb = qk_b[oc];
        const int h = oc0 >> 6;
        const int bh = b * NHD + h;
        const int dd = (oc0 & 16) + l16;
        if ((oc0 & 32) == 0) {
            const float qs = 0.17677669529663689f * 1.4426950408889634f;  // hd^-0.5 * log2e
#pragma unroll
            for (int r = 0; r < 4; ++r)
                Qb[((size_t)bh * NPIX + mb + r) * 32 + dd] = (__bf16)((acc[r] + bb) * qs);
        } else {
            __bf16* kp = Kf + ((size_t)(bh * 144 + (m0 >> 4)) * 64 + (dd >> 3) * 16 + quad * 4) * 8 + (dd & 7);
#pragma unroll
            for (int r = 0; r < 4; ++r) kp[r * 8] = (__bf16)(acc[r] + bb);
        }
    } else {
        const float bb = v_b[oc];
        const int h = oc0 >> 5;
        const int bh = b * NHD + h;
        const int half = (oc0 >> 4) & 1;
        const size_t fb = ((size_t)b * NCH + oc) * NPIX + mb;
        float4 vf_; float* vp = &vf_.x;
        union { __bf16 hh[4]; uint2 u; } pk;
#pragma unroll
        for (int r = 0; r < 4; ++r) {
            float v = acc[r] + bb;
            vp[r] = v; pk.hh[r] = (__bf16)v;
        }
        *(float4*)&v_bu[fb] = vf_;
        *(uint2*)&Vf[((size_t)(bh * 144 + (m0 >> 4)) * 64 + lane) * 8 + half * 4] = pk.u;
    }
}

// ---------------- MFMA 1x1 conv (proj/fc1/fc2), 4-wave blocks ----------------
// MODE 2: proj -> +resid(NCHW f32); out_f NCHW f32 (x1) + out_b NHWC bf16 (x1)
// MODE 3: fc1  -> silu; out_b NHWC bf16
// MODE 4: fc2  -> +resid(NCHW f32); out_f NCHW f32 (final)
template <int IC, int OC, int MODE>
__global__ __launch_bounds__(256) void convmm_k(
    const __bf16* __restrict__ A, const __bf16* __restrict__ W,
    const float* __restrict__ bias, const float* __restrict__ resid,
    float* __restrict__ out_f, __bf16* __restrict__ out_b) {
    const int tid = threadIdx.x;
    const int wave = tid >> 6, lane = tid & 63;
    const int l16 = lane & 15, quad = lane >> 4;
    const int m0 = blockIdx.x * 64 + wave * 16;
    const int oc0 = blockIdx.y * 16;
    const int b = blockIdx.z;

    const __bf16* aptr = A + ((size_t)b * NPIX + m0 + l16) * IC + quad * 8;
    const __bf16* bptr = W + (size_t)(oc0 + l16) * IC + quad * 8;

    f32x4 acc = {0.f, 0.f, 0.f, 0.f};
#pragma unroll 8
    for (int k = 0; k < IC; k += 32) {
        bf16x8 af = *(const bf16x8*)(aptr + k);
        bf16x8 bf = *(const bf16x8*)(bptr + k);
        acc = __builtin_amdgcn_mfma_f32_16x16x32_bf16(af, bf, acc, 0, 0, 0);
    }

    const int oc = oc0 + l16;
    const int mb = m0 + quad * 4;
    const float bb = bias[oc];

    if constexpr (MODE == 2) {
        const size_t fb = ((size_t)b * OC + oc) * NPIX + mb;
        float4 xr = *(const float4*)&resid[fb];
        const float* xp = &xr.x;
        float4 vf_; float* vp = &vf_.x;
#pragma unroll
        for (int r = 0; r < 4; ++r) {
            float v = acc[r] + bb + xp[r];
            vp[r] = v;
            out_b[((size_t)b * NPIX + mb + r) * OC + oc] = (__bf16)v;
        }
        *(float4*)&out_f[fb] = vf_;
    } else if constexpr (MODE == 3) {
#pragma unroll
        for (int r = 0; r < 4; ++r) {
            float v = acc[r] + bb;
            v = v / (1.f + __expf(-v));
            out_b[((size_t)b * NPIX + mb + r) * OC + oc] = (__bf16)v;
        }
    } else {  // MODE 4
        const size_t fb = ((size_t)b * OC + oc) * NPIX + mb;
        float4 xr = *(const float4*)&resid[fb];
        const float* xp = &xr.x;
        float4 vf_; float* vp = &vf_.x;
#pragma unroll
        for (int r = 0; r < 4; ++r) vp[r] = acc[r] + bb + xp[r];
        *(float4*)&out_f[fb] = vf_;
    }
}

// ---------------- depthwise 7x7, SAME, per (b,c) plane ----------------
__global__ __launch_bounds__(256) void dwconv_k(const float* __restrict__ vb,
                                                const float* __restrict__ pw,
                                                const float* __restrict__ pb,
                                                float* __restrict__ pe) {
    const int c = blockIdx.x, b = blockIdx.y, tid = threadIdx.x;
    __shared__ float plane[NPIX];
    __shared__ float wk[49];
    const size_t base = ((size_t)b * NCH + c) * NPIX;
    for (int i = tid; i < NPIX; i += 256) plane[i] = vb[base + i];
    if (tid < 49) wk[tid] = pw[c * 49 + tid];
    float bb = pb[c];
    __syncthreads();
    for (int p = tid; p < NPIX; p += 256) {
        int y = p / 48, x = p - y * 48;
        float s = bb;
#pragma unroll
        for (int ky = 0; ky < 7; ++ky) {
            int yy = y + ky - 3;
            if ((unsigned)yy < 48u) {
#pragma unroll
                for (int kx = 0; kx < 7; ++kx) {
                    int xx = x + kx - 3;
                    if ((unsigned)xx < 48u) s += wk[ky * 7 + kx] * plane[yy * 48 + xx];
                }
            }
        }
        pe[base + p] = s;
    }
}

// ---------------- MFMA flash attention v6: in-WG key-split 8 -----------------
// Block = 512 thr = 8 waves, SAME 32 queries; wave w handles tiles [w*18,(w+1)*18).
// Partials reduced via LDS; block normalizes, adds pe, writes NHWC bf16.
// grid (NPIX/32, NH, B). 9216 waves = 9/SIMD.
__global__ __launch_bounds__(512) void attn6_k(const __bf16* __restrict__ Qb,
                                               const __bf16* __restrict__ Kf,
                                               const __bf16* __restrict__ Vf,
                                               const float* __restrict__ pe,
                                               __bf16* __restrict__ opb) {
    const int tid = threadIdx.x;
    const int wave = tid >> 6, lane = tid & 63;
    const int l16 = lane & 15, quad = lane >> 4;
    const int qb = blockIdx.x * 32;
    const int h = blockIdx.y, b = blockIdx.z;
    const int bh = b * NHD + h;

    __shared__ float o_s[8][32][33];   // [wave][d][q], pad 33 -> <=2-way conflicts
    __shared__ float l_s[8][32];       // [wave][q]

    bf16x8 b_q0 = *(const bf16x8*)(Qb + ((size_t)bh * NPIX + qb + l16) * 32 + quad * 8);
    bf16x8 b_q1 = *(const bf16x8*)(Qb + ((size_t)bh * NPIX + qb + 16 + l16) * 32 + quad * 8);

    const __bf16* kf = Kf + ((size_t)(bh * 144 + wave * 18) * 64 + lane) * 8;
    const __bf16* vf = Vf + ((size_t)(bh * 144 + wave * 18) * 64 + lane) * 8;

    f32x4 o00 = {0.f,0.f,0.f,0.f}, o01 = {0.f,0.f,0.f,0.f};
    f32x4 o10 = {0.f,0.f,0.f,0.f}, o11 = {0.f,0.f,0.f,0.f};
    f32x4 l0 = {0.f,0.f,0.f,0.f}, l1 = {0.f,0.f,0.f,0.f};

#pragma unroll 3
    for (int t = 0; t < 18; ++t) {
        bf16x8 a_k = *(const bf16x8*)(kf + (size_t)t * 512);
        bf16x8 va  = *(const bf16x8*)(vf + (size_t)t * 512);
        f32x4 z = {0.f, 0.f, 0.f, 0.f};
        f32x4 s0 = __builtin_amdgcn_mfma_f32_16x16x32_bf16(a_k, b_q0, z, 0, 0, 0);
        f32x4 s1 = __builtin_amdgcn_mfma_f32_16x16x32_bf16(a_k, b_q1, z, 0, 0, 0);
        f32x4 p0, p1;
#pragma unroll
        for (int r = 0; r < 4; ++r) {
            p0[r] = __builtin_amdgcn_exp2f(s0[r]);
            p1[r] = __builtin_amdgcn_exp2f(s1[r]);
        }
        l0 += p0; l1 += p1;
        bf16x8 b0lo = {}, b0hi = {}, b1lo = {}, b1hi = {};
#pragma unroll
        for (int r = 0; r < 4; ++r) {
            __bf16 c0 = (__bf16)p0[r], c1 = (__bf16)p1[r];
            b0lo[r] = c0; b0hi[4 + r] = c0;
            b1lo[r] = c1; b1hi[4 + r] = c1;
        }
        o00 = __builtin_amdgcn_mfma_f32_16x16x32_bf16(va, b0lo, o00, 0, 0, 0);
        o01 = __builtin_amdgcn_mfma_f32_16x16x32_bf16(va, b0hi, o01, 0, 0, 0);
        o10 = __builtin_amdgcn_mfma_f32_16x16x32_bf16(va, b1lo, o10, 0, 0, 0);
        o11 = __builtin_amdgcn_mfma_f32_16x16x32_bf16(va, b1hi, o11, 0, 0, 0);
    }

    float ls0 = l0[0] + l0[1] + l0[2] + l0[3];
    ls0 += __shfl_xor(ls0, 16); ls0 += __shfl_xor(ls0, 32);
    float ls1 = l1[0] + l1[1] + l1[2] + l1[3];
    ls1 += __shfl_xor(ls1, 16); ls1 += __shfl_xor(ls1, 32);

#pragma unroll
    for (int r = 0; r < 4; ++r) {
        o_s[wave][quad * 4 + r][l16]           = o00[r];
        o_s[wave][16 + quad * 4 + r][l16]      = o01[r];
        o_s[wave][quad * 4 + r][16 + l16]      = o10[r];
        o_s[wave][16 + quad * 4 + r][16 + l16] = o11[r];
    }
    if (quad == 0) { l_s[wave][l16] = ls0; l_s[wave][16 + l16] = ls1; }
    __syncthreads();

    // final: 512 thr -> 1024 (q,d)-pairs; q-major for coalesced pe reads
    const int q = tid & 31;            // pixel within tile
    const int d0 = (tid >> 5) * 2;     // channel pair
    float l = 0.f;
#pragma unroll
    for (int w = 0; w < 8; ++w) l += l_s[w][q];
    const float inv = 1.f / l;
    float v0 = 0.f, v1 = 0.f;
#pragma unroll
    for (int w = 0; w < 8; ++w) {
        v0 += o_s[w][d0][q];
        v1 += o_s[w][d0 + 1][q];
    }
    const int n = qb + q;
    const int ch = h * HD + d0;
    v0 = v0 * inv + pe[((size_t)b * NCH + ch) * NPIX + n];
    v1 = v1 * inv + pe[((size_t)b * NCH + ch + 1) * NPIX + n];
    union { __bf16 hh[2]; unsigned u; } pk;
    pk.hh[0] = (__bf16)v0; pk.hh[1] = (__bf16)v1;
    *(unsigned*)&opb[((size_t)b * NPIX + n) * NCH + ch] = pk.u;
}

extern "C" void kernel_launch(void* const* d_in, const int* in_sizes, int n_in,
                              void* d_out, int out_size, void* d_ws, size_t ws_size,
                              hipStream_t stream) {
    const float* x    = (const float*)d_in[0];
    const float* qk_w = (const float*)d_in[1];
    const float* qk_b = (const float*)d_in[2];
    const float* v_w  = (const float*)d_in[3];
    const float* v_b  = (const float*)d_in[4];
    const float* pe_w = (const float*)d_in[5];
    const float* pe_b = (const float*)d_in[6];
    const float* pj_w = (const float*)d_in[7];
    const float* pj_b = (const float*)d_in[8];
    const float* f1_w = (const float*)d_in[9];
    const float* f1_b = (const float*)d_in[10];
    const float* f2_w = (const float*)d_in[11];
    const float* f2_b = (const float*)d_in[12];
    float* out = (float*)d_out;

    const int B = 2;
    const size_t plane = (size_t)NCH * NPIX;       // 589824
    const size_t bp = (size_t)B * plane;           // 1179648

    float* v_bu  = (float*)d_ws;                   // NCHW f32
    float* pe_bu = v_bu + bp;
    float* x1_f  = pe_bu + bp;
    __bf16* Xb   = (__bf16*)(x1_f + bp);           // NHWC bf16 [b][n][256]
    __bf16* opb  = Xb + bp;                        // NHWC bf16 (o/l + pe)
    __bf16* x1b  = opb + bp;                       // NHWC bf16
    __bf16* hb   = x1b + bp;                       // NHWC bf16 [b][n][512]
    __bf16* Qb   = hb + 2 * bp;                    // [bh][n][32] (pre-scaled)
    __bf16* Kf   = Qb + bp;                        // QK A-frag tiles
    __bf16* Vf   = Kf + bp;                        // PV A-frag tiles
    __bf16* Wall = Vf + bp;                        // 524288 bf16
    __bf16* Wq = Wall;
    __bf16* Wv = Wall + 131072;
    __bf16* Wp = Wall + 196608;
    __bf16* W1 = Wall + 262144;
    __bf16* W2 = Wall + 393216;

    // 1) x transpose + all weight casts
    prep_k<<<800, 256, 0, stream>>>(x, qk_w, v_w, pj_w, f1_w, f2_w, Xb, Wall);
    // 2) qk conv (-> Qb, Kf) + v conv (-> v_bu f32, Vf) fused
    qkv_k<<<dim3(36, 48, B), 256, 0, stream>>>(Xb, Wq, Wv, qk_b, v_b, Qb, Kf, v_bu, Vf);
    // 3) pe = dwconv7x7(v_full) + pe_b
    dwconv_k<<<dim3(NCH, B), 256, 0, stream>>>(v_bu, pe_w, pe_b, pe_bu);
    // 4) attention: in-WG key-split 8, normalize + pe add -> opb NHWC bf16
    attn6_k<<<dim3(NPIX / 32, NHD, B), 512, 0, stream>>>(Qb, Kf, Vf, pe_bu, opb);
    // 5) x1 = x + proj(o+pe): NCHW f32 + NHWC bf16
    convmm_k<256, 256, 2><<<dim3(36, 16, B), 256, 0, stream>>>(
        opb, Wp, pj_b, x, x1_f, x1b);
    // 6) h = silu(fc1(x1)) -> NHWC bf16
    convmm_k<256, 512, 3><<<dim3(36, 32, B), 256, 0, stream>>>(
        x1b, W1, f1_b, nullptr, nullptr, hb);
    // 7) out = x1 + fc2(h) -> NCHW f32
    convmm_k<512, 256, 4><<<dim3(36, 16, B), 256, 0, stream>>>(
        hb, W2, f2_b, x1_f, out, nullptr);
}